// Round 6
// baseline (113.466 us; speedup 1.0000x reference)
//
#include <hip/hip_runtime.h>
#include <math.h>

#define TEMP_F 0.07f
#define NCON 20
#define LDIM 512
#define NROWS 32768
#define NSEL 16384

// ws layout (floats):
// [2048 .. 2048+2*NROWS)  t2[r] = float2{ t_sz(r), t_nsz(r) }  (256 KB table)
//   t_b(r) = log( sum_{j kept_b} exp(sim[r,j]/T) ) - <hg_r, ebar_b>/(T*||hg_r||)

__device__ inline float dot4(float4 a, float4 b) {
    return a.x * b.x + a.y * b.y + a.z * b.z + a.w * b.w;
}

// ---------------------------------------------------------------------------
// Kernel 1: streaming pass with per-BLOCK ebar staging (prep dispatch folded
// in at block granularity, not r5's per-wave granularity).
// 8192 blocks x 256 threads = 4 waves, ONE ROW PER WAVE (r4's proven shape).
// Program order: (1) issue this wave's hg/sim loads  (2) build 4 KB ebar in
// LDS (20 KB of L2-warm all_emb reads per block)  (3) barrier  (4) math.
// The row's HBM latency hides under the ebar build.
// ---------------------------------------------------------------------------
__global__ __launch_bounds__(256) void stream_kernel(const float* __restrict__ hg,
                                                     const float* __restrict__ sim,
                                                     const float* __restrict__ all_emb,
                                                     const int* __restrict__ Psz,
                                                     const int* __restrict__ Pnsz,
                                                     float* __restrict__ ws,
                                                     float* __restrict__ out) {
    __shared__ float eb[1024];               // [0..512) ebar_sz, [512..1024) ebar_nsz
    const int tid  = threadIdx.x;
    const int wave = tid >> 6;
    const int lane = tid & 63;
    const int r    = blockIdx.x * 4 + wave;  // one row per wave

    // out is poisoned before every launch; gather atomics need 0.
    // The dispatch barrier orders this store before any gather atomic.
    if (blockIdx.x == 0 && tid == 0) out[0] = 0.f;

    // ---- (1) issue row loads first: latency overlaps the staging below ----
    const float4* rp = (const float4*)hg + (size_t)r * (LDIM / 4) + lane * 2;
    const float4 a0 = rp[0];
    const float4 a1 = rp[1];
    const bool  c20 = lane < NCON;
    const float sv  = c20 ? sim[(size_t)r * NCON + lane] : 0.f;

    // ---- (2) per-block ebar staging: thread t owns floats 2t, 2t+1 ----
    unsigned msz = (1u << NCON) - 1u, mnsz = (1u << NCON) - 1u;
    float sx = 0.f, sy = 0.f, nx = 0.f, ny = 0.f;
#pragma unroll
    for (int k = 0; k < 5; ++k) {
        const int cs = Psz[k], cn = Pnsz[k];   // wave-uniform scalar loads
        const float2 vs = *(const float2*)(all_emb + cs * LDIM + 2 * tid);
        const float2 vn = *(const float2*)(all_emb + cn * LDIM + 2 * tid);
        sx += vs.x; sy += vs.y; nx += vn.x; ny += vn.y;
        msz  &= ~(1u << cs);
        mnsz &= ~(1u << cn);
    }
    eb[2 * tid]           = sx * 0.2f;   // mean over 5 (duplicates counted,
    eb[2 * tid + 1]       = sy * 0.2f;   //  matches the reference)
    eb[512 + 2 * tid]     = nx * 0.2f;
    eb[512 + 2 * tid + 1] = ny * 0.2f;
    __syncthreads();

    // ---- (4) per-row math (identical to r4's proven rowterms body) ----
    const float4* eb4 = (const float4*)eb;
    const float4 es0 = eb4[lane * 2],       es1 = eb4[lane * 2 + 1];
    const float4 en0 = eb4[128 + lane * 2], en1 = eb4[128 + lane * 2 + 1];

    float ss = dot4(a0, a0) + dot4(a1, a1);
    float ds = dot4(a0, es0) + dot4(a1, es1);
    float dn = dot4(a0, en0) + dot4(a1, en1);

    const float invT = 1.0f / TEMP_F;
    const float ex = expf(sv * invT);
    float e_s = (c20 && (msz  & (1u << lane))) ? ex : 0.f;
    float e_n = (c20 && (mnsz & (1u << lane))) ? ex : 0.f;

#pragma unroll
    for (int off = 32; off; off >>= 1) {
        ss  += __shfl_xor(ss, off);
        ds  += __shfl_xor(ds, off);
        dn  += __shfl_xor(dn, off);
        e_s += __shfl_xor(e_s, off);
        e_n += __shfl_xor(e_n, off);
    }

    if (lane == 0) {
        const float rn = invT / fmaxf(sqrtf(ss), 1e-12f);
        ((float2*)(ws + 2048))[r] = make_float2(logf(e_s) - ds * rn,
                                                logf(e_n) - dn * rn);
    }
}

// ---------------------------------------------------------------------------
// Kernel 2: selection gather + reduce. 128 blocks x 256 = 32768 threads,
// one selection each (sz for t<16384, nsz above — wave-uniform split).
// Gather is a single 4B read from the L2-resident 256 KB table.
// 128 same-address atomics total (measured free in r0).
// ---------------------------------------------------------------------------
__global__ __launch_bounds__(256) void gather_kernel(const int* __restrict__ sz_idx,
                                                     const int* __restrict__ nsz_idx,
                                                     const float* __restrict__ ws,
                                                     float* __restrict__ out) {
    const float2* t2 = (const float2*)(ws + 2048);
    const int t = blockIdx.x * 256 + threadIdx.x;

    float v;
    if (t < NSEL) v = t2[sz_idx[t]].x;
    else          v = t2[nsz_idx[t - NSEL]].y;

#pragma unroll
    for (int off = 32; off; off >>= 1) v += __shfl_xor(v, off);

    __shared__ float red[4];
    const int lane = threadIdx.x & 63;
    const int w    = threadIdx.x >> 6;
    if (lane == 0) red[w] = v;
    __syncthreads();
    if (threadIdx.x == 0)
        atomicAdd(out, (red[0] + red[1] + red[2] + red[3]) * (1.0f / NSEL));
}

extern "C" void kernel_launch(void* const* d_in, const int* in_sizes, int n_in,
                              void* d_out, int out_size, void* d_ws, size_t ws_size,
                              hipStream_t stream) {
    const float* hg      = (const float*)d_in[0];
    const float* hg_corr = (const float*)d_in[1];
    const float* all_emb = (const float*)d_in[2];
    const int*   sz_idx  = (const int*)d_in[3];
    const int*   nsz_idx = (const int*)d_in[4];
    const int*   Psz     = (const int*)d_in[5];
    const int*   Pnsz    = (const int*)d_in[6];
    float* out = (float*)d_out;
    float* ws  = (float*)d_ws;

    stream_kernel<<<8192, 256, 0, stream>>>(hg, hg_corr, all_emb, Psz, Pnsz, ws, out);
    gather_kernel<<<128, 256, 0, stream>>>(sz_idx, nsz_idx, ws, out);
}

// Round 7
// 109.167 us; speedup vs baseline: 1.0394x; 1.0394x over previous
//
#include <hip/hip_runtime.h>
#include <math.h>

#define TEMP_F 0.07f
#define NCON 20
#define LDIM 512
#define NROWS 32768
#define NSEL 16384

// ws layout (floats unless noted):
// [0..511]      ebar_sz
// [512..1023]   ebar_nsz
// u32 [1024]    keep-mask sz  (bit j set => concept j kept)
// u32 [1025]    keep-mask nsz
// [2048 .. 2048+2*NROWS)  t2[r] = float2{ t_sz(r), t_nsz(r) }  (256 KB table)
//   t_b(r) = log( sum_{j kept_b} exp(sim[r,j]/T) ) - <hg_r, ebar_b>/(T*||hg_r||)

// ---------------------------------------------------------------------------
// Kernel 1: prep — 1 block x 512 threads. Concept-mean embeddings computed
// ONCE (r5/r6 showed replicating this per-wave/per-block costs ~4-5 us of
// L1/L2 traffic; a single tiny dispatch + L2-read of the 2 KB result wins).
// Also keep masks + zero out (out is poisoned before every launch).
// ---------------------------------------------------------------------------
__global__ __launch_bounds__(512) void prep_kernel(const float* __restrict__ all_emb,
                                                   const int* __restrict__ Psz,
                                                   const int* __restrict__ Pnsz,
                                                   float* __restrict__ ws,
                                                   float* __restrict__ out) {
    const int l = threadIdx.x;
    float ssz = 0.f, snsz = 0.f;
#pragma unroll
    for (int k = 0; k < 5; ++k) {
        ssz  += all_emb[Psz[k]  * LDIM + l];
        snsz += all_emb[Pnsz[k] * LDIM + l];
    }
    ws[l]       = ssz  * 0.2f;   // mean over 5 (duplicates counted, matches ref)
    ws[512 + l] = snsz * 0.2f;
    if (l == 0) {
        unsigned m = (1u << NCON) - 1u, m2 = (1u << NCON) - 1u;
#pragma unroll
        for (int k = 0; k < 5; ++k) { m &= ~(1u << Psz[k]); m2 &= ~(1u << Pnsz[k]); }
        ((unsigned*)ws)[1024] = m;
        ((unsigned*)ws)[1025] = m2;
        out[0] = 0.f;
    }
}

__device__ inline float dot4(float4 a, float4 b) {
    return a.x * b.x + a.y * b.y + a.z * b.z + a.w * b.w;
}

// ---------------------------------------------------------------------------
// Kernel 2: pure streaming pass, one row per wave, UNCONDITIONAL (measured:
// any data-dependent skip or staging on this path regresses — r1/r2/r5/r6).
// 8192 blocks x 256 threads = 32768 waves. HBM-bound on the 64 MB hg read.
// ---------------------------------------------------------------------------
__global__ __launch_bounds__(256) void rowterms_kernel(const float* __restrict__ hg,
                                                       const float* __restrict__ sim,
                                                       float* __restrict__ ws) {
    const int wave = threadIdx.x >> 6;
    const int lane = threadIdx.x & 63;
    const int r    = blockIdx.x * 4 + wave;

    const float4* eb4 = (const float4*)ws;   // 128 f4 ebar_sz, 128 f4 ebar_nsz
    const float4 es0 = eb4[lane * 2],       es1 = eb4[lane * 2 + 1];
    const float4 en0 = eb4[128 + lane * 2], en1 = eb4[128 + lane * 2 + 1];
    const unsigned msz  = ((const unsigned*)ws)[1024];
    const unsigned mnsz = ((const unsigned*)ws)[1025];

    const float4* rp = (const float4*)hg + (size_t)r * (LDIM / 4) + lane * 2;
    const float4 a0 = rp[0];
    const float4 a1 = rp[1];

    const bool  c20 = lane < NCON;
    const float sv  = c20 ? sim[(size_t)r * NCON + lane] : 0.f;

    float ss = dot4(a0, a0) + dot4(a1, a1);
    float ds = dot4(a0, es0) + dot4(a1, es1);
    float dn = dot4(a0, en0) + dot4(a1, en1);

    const float invT = 1.0f / TEMP_F;
    const float ex = expf(sv * invT);
    float e_s = (c20 && (msz  & (1u << lane))) ? ex : 0.f;
    float e_n = (c20 && (mnsz & (1u << lane))) ? ex : 0.f;

#pragma unroll
    for (int off = 32; off; off >>= 1) {
        ss  += __shfl_xor(ss, off);
        ds  += __shfl_xor(ds, off);
        dn  += __shfl_xor(dn, off);
        e_s += __shfl_xor(e_s, off);
        e_n += __shfl_xor(e_n, off);
    }

    if (lane == 0) {
        const float rn = invT / fmaxf(sqrtf(ss), 1e-12f);
        ((float2*)(ws + 2048))[r] = make_float2(logf(e_s) - ds * rn,
                                                logf(e_n) - dn * rn);
    }
}

// ---------------------------------------------------------------------------
// Kernel 3: selection gather + reduce. 128 blocks x 256 = 32768 threads,
// one selection each (sz for t<16384, nsz above — wave-uniform split).
// Gather is a single 4B read from the L2-resident 256 KB table.
// 128 same-address atomics total (measured free in r0).
// ---------------------------------------------------------------------------
__global__ __launch_bounds__(256) void gather_kernel(const int* __restrict__ sz_idx,
                                                     const int* __restrict__ nsz_idx,
                                                     const float* __restrict__ ws,
                                                     float* __restrict__ out) {
    const float2* t2 = (const float2*)(ws + 2048);
    const int t = blockIdx.x * 256 + threadIdx.x;

    float v;
    if (t < NSEL) v = t2[sz_idx[t]].x;
    else          v = t2[nsz_idx[t - NSEL]].y;

#pragma unroll
    for (int off = 32; off; off >>= 1) v += __shfl_xor(v, off);

    __shared__ float red[4];
    const int lane = threadIdx.x & 63;
    const int w    = threadIdx.x >> 6;
    if (lane == 0) red[w] = v;
    __syncthreads();
    if (threadIdx.x == 0)
        atomicAdd(out, (red[0] + red[1] + red[2] + red[3]) * (1.0f / NSEL));
}

extern "C" void kernel_launch(void* const* d_in, const int* in_sizes, int n_in,
                              void* d_out, int out_size, void* d_ws, size_t ws_size,
                              hipStream_t stream) {
    const float* hg      = (const float*)d_in[0];
    const float* hg_corr = (const float*)d_in[1];
    const float* all_emb = (const float*)d_in[2];
    const int*   sz_idx  = (const int*)d_in[3];
    const int*   nsz_idx = (const int*)d_in[4];
    const int*   Psz     = (const int*)d_in[5];
    const int*   Pnsz    = (const int*)d_in[6];
    float* out = (float*)d_out;
    float* ws  = (float*)d_ws;

    prep_kernel<<<1, 512, 0, stream>>>(all_emb, Psz, Pnsz, ws, out);
    rowterms_kernel<<<8192, 256, 0, stream>>>(hg, hg_corr, ws);
    gather_kernel<<<128, 256, 0, stream>>>(sz_idx, nsz_idx, ws, out);
}